// Round 2
// baseline (11066.010 us; speedup 1.0000x reference)
//
#include <hip/hip_runtime.h>

typedef unsigned short u16;
typedef short v8s __attribute__((ext_vector_type(8)));   // 8 x bf16 MFMA fragment
typedef float v4f __attribute__((ext_vector_type(4)));   // 4 x f32 accumulator

// Dims: B=256, T=512, D=32, H=256, 4H=1024, A=128, HOR=24, NQ=3
// Encoder: 256 blocks = 8 groups (32 batch rows) x 32 gate-column slices (8 units).
// Fused online attention; one group barrier per step; 516 pipelined steps.

__device__ __forceinline__ float bf2f(u16 u) {
  union { unsigned u; float f; } c; c.u = ((unsigned)u) << 16; return c.f;
}
__device__ __forceinline__ u16 f2bf(float f) {
  union { float f; unsigned u; } c; c.f = f;
  unsigned r = c.u + 0x7FFFu + ((c.u >> 16) & 1u);   // RTNE
  return (u16)(r >> 16);
}
__device__ __forceinline__ float sigf(float x) { return 1.f / (1.f + __expf(-x)); }
__device__ __forceinline__ float tanhfast(float x) {
  x = fminf(15.f, fmaxf(-15.f, x));
  float e = __expf(2.f * x);
  return (e - 1.f) / (e + 1.f);
}
// dtype-aware scalar input load
__device__ __forceinline__ float ldIn(const void* p, size_t i, int isbf) {
  return isbf ? bf2f(((const u16*)p)[i]) : ((const float*)p)[i];
}
// dtype-aware 8-contiguous-element load -> bf16 fragment (hi only)
__device__ __forceinline__ v8s ld8hi(const void* p, size_t eoff, int isbf) {
  if (isbf) return *(const v8s*)((const u16*)p + eoff);
  const float* f = (const float*)p + eoff;
  v8s r;
#pragma unroll
  for (int j = 0; j < 8; ++j) r[j] = (short)f2bf(f[j]);
  return r;
}
// dtype-aware 8-element load with hi/lo split (lo = residual; 0 in bf16 world)
__device__ __forceinline__ void ld8split(const void* p, size_t eoff, int isbf,
                                         v8s& hi, v8s& lo) {
  if (isbf) {
    hi = *(const v8s*)((const u16*)p + eoff);
    lo = v8s{0, 0, 0, 0, 0, 0, 0, 0};
  } else {
    const float* f = (const float*)p + eoff;
#pragma unroll
    for (int j = 0; j < 8; ++j) {
      u16 h = f2bf(f[j]);
      hi[j] = (short)h;
      lo[j] = (short)f2bf(f[j] - bf2f(h));
    }
  }
}
// fp32 source -> hi/lo split fragments
__device__ __forceinline__ void ld8f32split(const float* f, v8s& hi, v8s& lo) {
#pragma unroll
  for (int j = 0; j < 8; ++j) {
    u16 h = f2bf(f[j]);
    hi[j] = (short)h;
    lo[j] = (short)f2bf(f[j] - bf2f(h));
  }
}
#define MFMA(a, b, c) __builtin_amdgcn_mfma_f32_16x16x32_bf16(a, b, c, 0, 0, 0)

// Group barrier across 32 blocks, monotone counter (zeroed each launch).
__device__ __forceinline__ void group_barrier(int* cnt, int expected) {
  __syncthreads();   // drains vmcnt for all waves before leader publishes
  if (threadIdx.x == 0) {
    __threadfence();
    __hip_atomic_fetch_add(cnt, 1, __ATOMIC_RELEASE, __HIP_MEMORY_SCOPE_AGENT);
    while (__hip_atomic_load(cnt, __ATOMIC_RELAXED, __HIP_MEMORY_SCOPE_AGENT) < expected) {}
    __threadfence();
  }
  __syncthreads();
}

// Input-dtype sniff: even-index ushorts of a fp32 buffer are low mantissa bits
// (random bf16 exponent, ~17% sane); of a bf16 buffer they are real values (~100%).
__global__ void sniff_kernel(const u16* __restrict__ w, int* __restrict__ flag) {
  __shared__ int cnt;
  if (threadIdx.x == 0) cnt = 0;
  __syncthreads();
  int ok = 0;
  for (int i = threadIdx.x; i < 1024; i += 256) {
    u16 u = w[2 * i];
    int e = (u >> 7) & 0xFF;
    ok += (u == 0 || (e >= 97 && e <= 140)) ? 1 : 0;
  }
  atomicAdd(&cnt, ok);
  __syncthreads();
  if (threadIdx.x == 0) *flag = (cnt >= 768) ? 1 : 0;
}

// ---------------- Encoder with fused online-softmax attention ----------------
__global__ __launch_bounds__(256) void enc_kernel(
    const void* __restrict__ x,
    const void* __restrict__ eWih0, const void* __restrict__ eWhh0, const void* __restrict__ eb0,
    const void* __restrict__ eWih1, const void* __restrict__ eWhh1, const void* __restrict__ eb1,
    const void* __restrict__ aW, const void* __restrict__ aV,
    u16* __restrict__ hx0hi, u16* __restrict__ hx0lo,
    u16* __restrict__ hx1hi, u16* __restrict__ hx1lo,
    float* __restrict__ ctx, float* __restrict__ ePG, float* __restrict__ eG,
    int* __restrict__ cnt, const int* __restrict__ flagp) {
  __shared__ v8s w0s[1152];              // [nt(2)][kt(9)][lane(64)]  18 KB
  __shared__ v8s w1s[2048];              // [nt(2)][kt(16)][lane(64)] 32 KB
  __shared__ float gb0[32 * 33], gb1[32 * 33];
  __shared__ float b0s[32], b1s[32];
  __shared__ float eL[32];
  __shared__ float attRed[2];

  const int isbf = *flagp;
  const int tid = threadIdx.x, blk = blockIdx.x;
  const int grp = blk & 7;               // XCD-co-located group of 32 blocks
  const int gs  = blk >> 3;              // gate-column slice (8 hidden units)

  // ---- startup: gather B-fragments straight from global weights ----
  for (int i = tid; i < 1152; i += 256) {
    int lane = i & 63, q = i >> 6;
    int kt = q % 9, nt = q / 9;
    int nl = nt * 16 + (lane & 15);
    int gidx = (nl >> 3) * 256 + gs * 8 + (nl & 7);
    int kq = (lane >> 4) * 8;
    w0s[i] = (kt == 0) ? ld8hi(eWih0, (size_t)gidx * 32 + kq, isbf)
                       : ld8hi(eWhh0, (size_t)gidx * 256 + (kt - 1) * 32 + kq, isbf);
  }
  for (int i = tid; i < 2048; i += 256) {
    int lane = i & 63, q = i >> 6;
    int kt = q & 15, nt = q >> 4;
    int nl = nt * 16 + (lane & 15);
    int gidx = (nl >> 3) * 256 + gs * 8 + (nl & 7);
    int kq = (lane >> 4) * 8;
    w1s[i] = (kt < 8) ? ld8hi(eWhh1, (size_t)gidx * 256 + kt * 32 + kq, isbf)
                      : ld8hi(eWih1, (size_t)gidx * 256 + (kt - 8) * 32 + kq, isbf);
  }
  if (tid < 32) {
    int gidx = (tid >> 3) * 256 + gs * 8 + (tid & 7);
    b0s[tid] = ldIn(eb0, gidx, isbf);
    b1s[tid] = ldIn(eb1, gidx, isbf);
  }

  const int lane = tid & 63, wv = tid >> 6;
  const int ln = lane & 15, lq = lane >> 4;
  const int Mt = wv >> 1, Nt = wv & 1;
  const int bRow = grp * 32 + Mt * 16 + ln;
  const int na = gs & 7, kc = gs >> 3, ka = kc * 2 + Nt;

  v8s aWB;                               // aW B-frag: B[k][n]=aW[h][a]
#pragma unroll
  for (int j = 0; j < 8; ++j)
    aWB[j] = (short)f2bf(ldIn(aW, (size_t)(ka * 32 + lq * 8 + j) * 128 + na * 16 + ln, isbf));
  const float aVr = (tid < 128) ? ldIn(aV, (size_t)tid, isbf) : 0.f;

  const int urow = tid >> 3, uu = tid & 7;
  const int ubRow = grp * 32 + urow;
  const int guIdx = gs * 8 + uu;

  float c0 = 0.f, c1 = 0.f;
  float mS = -1e30f, lS = 0.f, ctxA = 0.f;
  float h_d1 = 0.f, h_d2 = 0.f, h_d3 = 0.f;
  int* bcnt = cnt + grp * 32;
  float* ePGg = ePG + (size_t)grp * 65536;   // [par(2)][ka(8)][row(32)][a(128)]
  float* eGg = eG + grp * 64;                // [par(2)][row(32)]

  __syncthreads();

  // pipeline: t: L0 h0[t] | L1 h1[t-1] | attnMFMA h1[t-2] | e-final h1[t-3] | ctx h1[t-4]
  for (int t = 0; t <= 515; ++t) {
    const int rB = (t + 1) & 1, wB = t & 1;
    if (t >= 4 && tid < 32) eL[tid] = eGg[((t - 1) & 1) * 32 + tid];
    // stage4: finalize e[t-3]
    if (t >= 3 && t <= 514 && tid < 128) {
      const float* bp = ePGg + ((t - 1) & 1) * 32768 + gs * 128 + tid;
      float s = 0.f;
#pragma unroll
      for (int kk = 0; kk < 8; ++kk) s += bp[kk * 4096];
      s = tanhfast(s) * aVr;
#pragma unroll
      for (int off = 32; off; off >>= 1) s += __shfl_down(s, off);
      if ((tid & 63) == 0) attRed[tid >> 6] = s;
    }
    v4f acc0 = {0.f, 0.f, 0.f, 0.f}, acc1 = {0.f, 0.f, 0.f, 0.f}, accA = {0.f, 0.f, 0.f, 0.f};
    // L0 gates for h0[t]
    if (t < 512) {
      v8s xh, xl;
      ld8split(x, (size_t)(bRow * 512 + t) * 32 + lq * 8, isbf, xh, xl);
      acc0 = MFMA(xh, w0s[Nt * 576 + lane], acc0);
      if (!isbf) acc0 = MFMA(xl, w0s[Nt * 576 + lane], acc0);
      const u16* hh = hx0hi + rB * 65536 + bRow * 256;
      const u16* hl = hx0lo + rB * 65536 + bRow * 256;
#pragma unroll
      for (int kt = 1; kt < 9; ++kt) {
        int off = (kt - 1) * 32 + lq * 8;
        acc0 = MFMA(*(const v8s*)(hh + off), w0s[Nt * 576 + kt * 64 + lane], acc0);
        acc0 = MFMA(*(const v8s*)(hl + off), w0s[Nt * 576 + kt * 64 + lane], acc0);
      }
    }
    // L1 gates for h1[t-1] from [h1[t-2] ; h0[t-1]]
    if (t >= 1 && t <= 512) {
      const u16* h1h = hx1hi + wB * 65536 + bRow * 256;
      const u16* h1l = hx1lo + wB * 65536 + bRow * 256;
      const u16* h0h = hx0hi + rB * 65536 + bRow * 256;
      const u16* h0l = hx0lo + rB * 65536 + bRow * 256;
#pragma unroll
      for (int kt = 0; kt < 8; ++kt) {
        int off = kt * 32 + lq * 8;
        acc1 = MFMA(*(const v8s*)(h1h + off), w1s[Nt * 1024 + kt * 64 + lane], acc1);
        acc1 = MFMA(*(const v8s*)(h1l + off), w1s[Nt * 1024 + kt * 64 + lane], acc1);
      }
#pragma unroll
      for (int kt = 8; kt < 16; ++kt) {
        int off = (kt - 8) * 32 + lq * 8;
        acc1 = MFMA(*(const v8s*)(h0h + off), w1s[Nt * 1024 + kt * 64 + lane], acc1);
        acc1 = MFMA(*(const v8s*)(h0l + off), w1s[Nt * 1024 + kt * 64 + lane], acc1);
      }
    }
    // stage3: attention partials for h1[t-2] (same buffer the L1 loop reads)
    if (t >= 2 && t <= 513) {
      const u16* h1h = hx1hi + wB * 65536 + bRow * 256 + ka * 32 + lq * 8;
      const u16* h1l = hx1lo + wB * 65536 + bRow * 256 + ka * 32 + lq * 8;
      accA = MFMA(*(const v8s*)h1h, aWB, accA);
      accA = MFMA(*(const v8s*)h1l, aWB, accA);
      float* ep = ePGg + wB * 32768 + ka * 4096 + (Mt * 16 + lq * 4) * 128 + na * 16 + ln;
#pragma unroll
      for (int r = 0; r < 4; ++r) ep[r * 128] = accA[r];
    }
    // C-frags -> LDS (C/D: col=lane&15, row=(lane>>4)*4+reg)
    if (t < 512) {
      int baseR = Mt * 16 + lq * 4, colC = Nt * 16 + ln;
#pragma unroll
      for (int r = 0; r < 4; ++r) gb0[(baseR + r) * 33 + colC] = acc0[r];
    }
    if (t >= 1 && t <= 512) {
      int baseR = Mt * 16 + lq * 4, colC = Nt * 16 + ln;
#pragma unroll
      for (int r = 0; r < 4; ++r) gb1[(baseR + r) * 33 + colC] = acc1[r];
    }
    __syncthreads();
    if (t >= 3 && t <= 514 && tid == 0) eGg[wB * 32 + gs] = attRed[0] + attRed[1];
    // L0 update
    if (t < 512) {
      float gi = gb0[urow * 33 + uu] + b0s[uu];
      float gf = gb0[urow * 33 + 8 + uu] + b0s[8 + uu];
      float gg = gb0[urow * 33 + 16 + uu] + b0s[16 + uu];
      float go = gb0[urow * 33 + 24 + uu] + b0s[24 + uu];
      c0 = sigf(gf) * c0 + sigf(gi) * tanhfast(gg);
      float h = sigf(go) * tanhfast(c0);
      u16 hh16 = f2bf(h);
      int o = wB * 65536 + ubRow * 256 + guIdx;
      hx0hi[o] = hh16;
      hx0lo[o] = f2bf(h - bf2f(hh16));
    }
    // L1 update
    float hnew = h_d1;
    if (t >= 1 && t <= 512) {
      float gi = gb1[urow * 33 + uu] + b1s[uu];
      float gf = gb1[urow * 33 + 8 + uu] + b1s[8 + uu];
      float gg = gb1[urow * 33 + 16 + uu] + b1s[16 + uu];
      float go = gb1[urow * 33 + 24 + uu] + b1s[24 + uu];
      c1 = sigf(gf) * c1 + sigf(gi) * tanhfast(gg);
      float h = sigf(go) * tanhfast(c1);
      u16 hh16 = f2bf(h);
      int o = rB * 65536 + ubRow * 256 + guIdx;
      hx1hi[o] = hh16;
      hx1lo[o] = f2bf(h - bf2f(hh16));
      hnew = h;
    }
    // stage5: online-softmax context accumulation for h1[t-4]
    if (t >= 4) {
      float e = eL[urow];
      float nm = fmaxf(mS, e);
      float al = __expf(mS - nm);
      float p = __expf(e - nm);
      lS = lS * al + p;
      ctxA = ctxA * al + p * h_d3;
      mS = nm;
    }
    h_d3 = h_d2; h_d2 = h_d1; h_d1 = hnew;
    group_barrier(bcnt, 32 * (t + 1));
  }
  ctx[ubRow * 256 + guIdx] = ctxA / lS;
}

// ---------------- Decoder: 24 steps, 2 barriers/step, + projection ----------------
__global__ __launch_bounds__(256) void dec_kernel(
    const void* __restrict__ x,
    const void* __restrict__ dWih0, const void* __restrict__ dWhh0, const void* __restrict__ db0,
    const void* __restrict__ dWih1, const void* __restrict__ dWhh1, const void* __restrict__ db1,
    const void* __restrict__ qW, const void* __restrict__ qb,
    const float* __restrict__ ctx,
    u16* __restrict__ hx0hi, u16* __restrict__ hx0lo,
    u16* __restrict__ hx1hi, u16* __restrict__ hx1lo,
    float* __restrict__ dinpG, void* __restrict__ out,
    int* __restrict__ cnt, const int* __restrict__ flagp) {
  __shared__ v8s w0s[1024];              // [nt(2)][kt(8)][lane] 16 KB
  __shared__ v8s w1s[2048];              // 32 KB
  __shared__ float gb0[32 * 33], gb1[32 * 33];
  __shared__ float b0s[32], b1s[32], w0v[32];
  __shared__ float dinpS[32];

  const int isbf = *flagp;
  const int tid = threadIdx.x, blk = blockIdx.x;
  const int grp = blk & 7, gs = blk >> 3;

  for (int i = tid; i < 1024; i += 256) {
    int lane = i & 63, q = i >> 6;
    int kt = q & 7, nt = q >> 3;
    int nl = nt * 16 + (lane & 15);
    int gidx = (nl >> 3) * 256 + gs * 8 + (nl & 7);
    int kq = (lane >> 4) * 8;
    w0s[i] = ld8hi(dWhh0, (size_t)gidx * 256 + kt * 32 + kq, isbf);
  }
  for (int i = tid; i < 2048; i += 256) {
    int lane = i & 63, q = i >> 6;
    int kt = q & 15, nt = q >> 4;
    int nl = nt * 16 + (lane & 15);
    int gidx = (nl >> 3) * 256 + gs * 8 + (nl & 7);
    int kq = (lane >> 4) * 8;
    w1s[i] = (kt < 8) ? ld8hi(dWhh1, (size_t)gidx * 256 + kt * 32 + kq, isbf)
                      : ld8hi(dWih1, (size_t)gidx * 256 + (kt - 8) * 32 + kq, isbf);
  }
  if (tid < 32) {
    int gidx = (tid >> 3) * 256 + gs * 8 + (tid & 7);
    b0s[tid] = ldIn(db0, gidx, isbf);
    b1s[tid] = ldIn(db1, gidx, isbf);
    w0v[tid] = ldIn(dWih0, gidx, isbf);
  }

  const int lane = tid & 63, wv = tid >> 6;
  const int ln = lane & 15, lq = lane >> 4;
  const int Mt = wv >> 1, Nt = wv & 1;
  const int bRow = grp * 32 + Mt * 16 + ln;
  const int urow = tid >> 3, uu = tid & 7;
  const int ubRow = grp * 32 + urow;
  const int guIdx = gs * 8 + uu;

  float c0 = ctx[ubRow * 256 + guIdx];
  float c1 = c0;
  int* bcnt = cnt + grp * 32;

  __syncthreads();

  for (int t = 0; t < 24; ++t) {
    const int rB = (t + 1) & 1, wB = t & 1;
    if (tid < 32) {
      int bR = grp * 32 + tid;
      dinpS[tid] = (t == 0) ? ldIn(x, (size_t)bR * 512 * 32 + 511 * 32 + 31, isbf)
                            : dinpG[((t - 1) & 1) * 256 + bR];
    }
    // L0 gates from h0d[t-1] (t=0: context, fp32-split)
    v4f acc0 = {0.f, 0.f, 0.f, 0.f};
    if (t == 0) {
#pragma unroll
      for (int kt = 0; kt < 8; ++kt) {
        v8s hi, lo;
        ld8f32split(ctx + bRow * 256 + kt * 32 + lq * 8, hi, lo);
        acc0 = MFMA(hi, w0s[Nt * 512 + kt * 64 + lane], acc0);
        acc0 = MFMA(lo, w0s[Nt * 512 + kt * 64 + lane], acc0);
      }
    } else {
      const u16* hh = hx0hi + rB * 65536 + bRow * 256;
      const u16* hl = hx0lo + rB * 65536 + bRow * 256;
#pragma unroll
      for (int kt = 0; kt < 8; ++kt) {
        int off = kt * 32 + lq * 8;
        acc0 = MFMA(*(const v8s*)(hh + off), w0s[Nt * 512 + kt * 64 + lane], acc0);
        acc0 = MFMA(*(const v8s*)(hl + off), w0s[Nt * 512 + kt * 64 + lane], acc0);
      }
    }
    {
      int baseR = Mt * 16 + lq * 4, colC = Nt * 16 + ln;
#pragma unroll
      for (int r = 0; r < 4; ++r) gb0[(baseR + r) * 33 + colC] = acc0[r];
    }
    __syncthreads();
    {
      float di = dinpS[urow];
      float gi = gb0[urow * 33 + uu] + b0s[uu] + di * w0v[uu];
      float gf = gb0[urow * 33 + 8 + uu] + b0s[8 + uu] + di * w0v[8 + uu];
      float gg = gb0[urow * 33 + 16 + uu] + b0s[16 + uu] + di * w0v[16 + uu];
      float go = gb0[urow * 33 + 24 + uu] + b0s[24 + uu] + di * w0v[24 + uu];
      c0 = sigf(gf) * c0 + sigf(gi) * tanhfast(gg);
      float h = sigf(go) * tanhfast(c0);
      u16 hh16 = f2bf(h);
      int o = wB * 65536 + ubRow * 256 + guIdx;
      hx0hi[o] = hh16;
      hx0lo[o] = f2bf(h - bf2f(hh16));
    }
    group_barrier(bcnt, 32 * (2 * t + 1));
    // L1 gates from [h1d[t-1] ; h0d[t]]
    v4f acc1 = {0.f, 0.f, 0.f, 0.f};
    {
      const u16* h0h = hx0hi + wB * 65536 + bRow * 256;
      const u16* h0l = hx0lo + wB * 65536 + bRow * 256;
      if (t == 0) {
#pragma unroll
        for (int kt = 0; kt < 8; ++kt) {
          v8s hi, lo;
          ld8f32split(ctx + bRow * 256 + kt * 32 + lq * 8, hi, lo);
          acc1 = MFMA(hi, w1s[Nt * 1024 + kt * 64 + lane], acc1);
          acc1 = MFMA(lo, w1s[Nt * 1024 + kt * 64 + lane], acc1);
        }
      } else {
        const u16* h1h = hx1hi + rB * 65536 + bRow * 256;
        const u16* h1l = hx1lo + rB * 65536 + bRow * 256;
#pragma unroll
        for (int kt = 0; kt < 8; ++kt) {
          int off = kt * 32 + lq * 8;
          acc1 = MFMA(*(const v8s*)(h1h + off), w1s[Nt * 1024 + kt * 64 + lane], acc1);
          acc1 = MFMA(*(const v8s*)(h1l + off), w1s[Nt * 1024 + kt * 64 + lane], acc1);
        }
      }
#pragma unroll
      for (int kt = 8; kt < 16; ++kt) {
        int off = (kt - 8) * 32 + lq * 8;
        acc1 = MFMA(*(const v8s*)(h0h + off), w1s[Nt * 1024 + kt * 64 + lane], acc1);
        acc1 = MFMA(*(const v8s*)(h0l + off), w1s[Nt * 1024 + kt * 64 + lane], acc1);
      }
    }
    {
      int baseR = Mt * 16 + lq * 4, colC = Nt * 16 + ln;
#pragma unroll
      for (int r = 0; r < 4; ++r) gb1[(baseR + r) * 33 + colC] = acc1[r];
    }
    __syncthreads();
    {
      float gi = gb1[urow * 33 + uu] + b1s[uu];
      float gf = gb1[urow * 33 + 8 + uu] + b1s[8 + uu];
      float gg = gb1[urow * 33 + 16 + uu] + b1s[16 + uu];
      float go = gb1[urow * 33 + 24 + uu] + b1s[24 + uu];
      c1 = sigf(gf) * c1 + sigf(gi) * tanhfast(gg);
      float h = sigf(go) * tanhfast(c1);
      u16 hh16 = f2bf(h);
      int o = wB * 65536 + ubRow * 256 + guIdx;
      hx1hi[o] = hh16;
      hx1lo[o] = f2bf(h - bf2f(hh16));
      if (gs == 0 && uu == 0) dinpG[wB * 256 + ubRow] = h;
    }
    group_barrier(bcnt, 32 * (2 * t + 2));
  }
  // projection: preds[b][qo] = sum_h h1d[23][b][h]*qW[qo][h] + qb[qo]
  if (gs < 24 && tid < 96) {
    int r = tid / 3, p = tid % 3;
    int qo = gs * 3 + p;
    int bR = grp * 32 + r;
    const u16* hh = hx1hi + 65536 + bR * 256;
    const u16* hl = hx1lo + 65536 + bR * 256;
    float s = ldIn(qb, qo, isbf);
    for (int h = 0; h < 256; ++h)
      s += (bf2f(hh[h]) + bf2f(hl[h])) * ldIn(qW, (size_t)qo * 256 + h, isbf);
    if (isbf) ((u16*)out)[bR * 72 + qo] = f2bf(s);
    else      ((float*)out)[bR * 72 + qo] = s;
  }
}

extern "C" void kernel_launch(void* const* d_in, const int* in_sizes, int n_in,
                              void* d_out, int out_size, void* d_ws, size_t ws_size,
                              hipStream_t stream) {
  const void* x     = d_in[0];
  const void* eWih0 = d_in[1];
  const void* eWhh0 = d_in[2];
  const void* eb0   = d_in[3];
  const void* eWih1 = d_in[4];
  const void* eWhh1 = d_in[5];
  const void* eb1   = d_in[6];
  const void* dWih0 = d_in[7];
  const void* dWhh0 = d_in[8];
  const void* db0   = d_in[9];
  const void* dWih1 = d_in[10];
  const void* dWhh1 = d_in[11];
  const void* db1   = d_in[12];
  const void* aW    = d_in[13];
  const void* aV    = d_in[14];
  const void* qW    = d_in[15];
  const void* qb    = d_in[16];

  char* wsb = (char*)d_ws;
  u16*   hx0hi = (u16*)(wsb + 0);              // 262144
  u16*   hx0lo = (u16*)(wsb + 262144);         // 262144
  u16*   hx1hi = (u16*)(wsb + 524288);         // 262144
  u16*   hx1lo = (u16*)(wsb + 786432);         // 262144
  int*   cntE  = (int*)(wsb + 1048576);        // 1024
  int*   cntD  = (int*)(wsb + 1049600);        // 1024
  int*   flag  = (int*)(wsb + 1050624);        // 256
  float* eG    = (float*)(wsb + 1050880);      // 2048  [8][2][32]
  float* dinpG = (float*)(wsb + 1052928);      // 2048  [2][256]
  float* ctx   = (float*)(wsb + 1054976);      // 262144
  float* ePG   = (float*)(wsb + 1317120);      // 2097152 [8][2][8][32][128]
  // total ws: 3,414,272 bytes

  hipMemsetAsync(wsb, 0, 1050624, stream);     // hx + barrier counters

  sniff_kernel<<<1, 256, 0, stream>>>((const u16*)eWhh0, flag);
  enc_kernel<<<256, 256, 0, stream>>>(x, eWih0, eWhh0, eb0, eWih1, eWhh1, eb1,
                                      aW, aV, hx0hi, hx0lo, hx1hi, hx1lo,
                                      ctx, ePG, eG, cntE, flag);
  dec_kernel<<<256, 256, 0, stream>>>(x, dWih0, dWhh0, db0, dWih1, dWhh1, db1,
                                      qW, qb, ctx, hx0hi, hx0lo, hx1hi, hx1lo,
                                      dinpG, d_out, cntD, flag);
}

// Round 3
// 3256.539 us; speedup vs baseline: 3.3981x; 3.3981x over previous
//
#include <hip/hip_runtime.h>

typedef unsigned short u16;
typedef unsigned int u32;
typedef unsigned long long u64;
typedef short v8s __attribute__((ext_vector_type(8)));
typedef float v4f __attribute__((ext_vector_type(4)));

// Dims: B=256, T=512, D=32, H=256, 4H=1024, A=128, HOR=24, NQ=3
// Topology: 256 blocks = 16 groups (16 batch rows) x 16 slices (16 units = 64 gate-cols).
// Weights live in registers as MFMA B-frags; LDS only stages the per-step h exchange.
// Exchange: packed u32 (bf16 hi | lo<<16) via relaxed agent atomics (IF$-coherent),
// group flag via relaxed agent atomic add. NO __threadfence (avoids buffer_wbl2 L2 flush).

__device__ __forceinline__ float bf2f(u16 u) { union { u32 u; float f; } c; c.u = ((u32)u) << 16; return c.f; }
__device__ __forceinline__ u16 f2bf(float f) {
  union { float f; u32 u; } c; c.f = f;
  u32 r = c.u + 0x7FFFu + ((c.u >> 16) & 1u);   // RTNE
  return (u16)(r >> 16);
}
__device__ __forceinline__ float sigf(float x) { return 1.f / (1.f + __expf(-x)); }
__device__ __forceinline__ float tanhfast(float x) {
  x = fminf(15.f, fmaxf(-15.f, x));
  float e = __expf(2.f * x);
  return (e - 1.f) / (e + 1.f);
}
__device__ __forceinline__ float ldIn(const void* p, size_t i, int isbf) {
  return isbf ? bf2f(((const u16*)p)[i]) : ((const float*)p)[i];
}
__device__ __forceinline__ v8s ld8hi(const void* p, size_t e, int isbf) {
  if (isbf) return *(const v8s*)((const u16*)p + e);
  const float* f = (const float*)p + e;
  v8s r;
#pragma unroll
  for (int j = 0; j < 8; ++j) r[j] = (short)f2bf(f[j]);
  return r;
}
__device__ __forceinline__ void ld8split(const void* p, size_t e, int isbf, v8s& hi, v8s& lo) {
  if (isbf) {
    hi = *(const v8s*)((const u16*)p + e);
    lo = v8s{0, 0, 0, 0, 0, 0, 0, 0};
  } else {
    const float* f = (const float*)p + e;
#pragma unroll
    for (int j = 0; j < 8; ++j) {
      u16 h = f2bf(f[j]);
      hi[j] = (short)h;
      lo[j] = (short)f2bf(f[j] - bf2f(h));
    }
  }
}
#define MFMA(a, b, c) __builtin_amdgcn_mfma_f32_16x16x32_bf16(a, b, c, 0, 0, 0)

__device__ __forceinline__ u64 aload64(const u64* p) {
  return __hip_atomic_load(p, __ATOMIC_RELAXED, __HIP_MEMORY_SCOPE_AGENT);
}
__device__ __forceinline__ u32 aload32(const u32* p) {
  return __hip_atomic_load(p, __ATOMIC_RELAXED, __HIP_MEMORY_SCOPE_AGENT);
}
__device__ __forceinline__ void astore32(u32* p, u32 v) {
  __hip_atomic_store(p, v, __ATOMIC_RELAXED, __HIP_MEMORY_SCOPE_AGENT);
}

// 16-block group barrier: monotone counter, relaxed agent atomics only.
// __syncthreads drains each wave's vmcnt, so all data stores reached the
// coherence point before the leader's add becomes visible.
__device__ __forceinline__ void group_barrier(int* cnt, int expected) {
  __syncthreads();
  if (threadIdx.x == 0) {
    __hip_atomic_fetch_add(cnt, 1, __ATOMIC_RELAXED, __HIP_MEMORY_SCOPE_AGENT);
    while (__hip_atomic_load(cnt, __ATOMIC_RELAXED, __HIP_MEMORY_SCOPE_AGENT) < expected) {}
  }
  __syncthreads();
}

// Stage 16 rows x 256 units of packed (hi|lo<<16) u32 into de-interleaved LDS
// arrays (row stride 264 u16, 16B-aligned rows).
__device__ __forceinline__ void stage_u32(u16* dhi, u16* dlo, const u32* src, int tid) {
  const u64* s = (const u64*)src;
#pragma unroll
  for (int i = 0; i < 4; ++i) {
    int base = i * 512 + tid * 2;          // u64 index in [16][128]
    int row = base >> 7, jp = base & 127;  // jp even
    u64 wa = aload64(s + row * 128 + jp);
    u64 wb = aload64(s + row * 128 + jp + 1);
    u32 a0 = (u32)wa, a1 = (u32)(wa >> 32), b0 = (u32)wb, b1 = (u32)(wb >> 32);
    u32 hp0 = (a0 & 0xFFFFu) | (a1 << 16), lp0 = (a0 >> 16) | (a1 & 0xFFFF0000u);
    u32 hp1 = (b0 & 0xFFFFu) | (b1 << 16), lp1 = (b0 >> 16) | (b1 & 0xFFFF0000u);
    *(u64*)((u32*)(dhi + row * 264) + jp) = ((u64)hp1 << 32) | hp0;
    *(u64*)((u32*)(dlo + row * 264) + jp) = ((u64)lp1 << 32) | lp0;
  }
}
// Same but from fp32 source (ctx), hi/lo computed on the fly.
__device__ __forceinline__ void stage_f32(u16* dhi, u16* dlo, const float* src, int tid) {
#pragma unroll
  for (int i = 0; i < 8; ++i) {
    int e = i * 512 + tid * 2;             // element idx, even
    int row = e >> 8, jc = e & 255;
    float f0 = src[row * 256 + jc], f1 = src[row * 256 + jc + 1];
    u16 h0 = f2bf(f0), h1 = f2bf(f1);
    u16 l0 = f2bf(f0 - bf2f(h0)), l1 = f2bf(f1 - bf2f(h1));
    ((u32*)(dhi + row * 264))[jc >> 1] = (u32)h0 | ((u32)h1 << 16);
    ((u32*)(dlo + row * 264))[jc >> 1] = (u32)l0 | ((u32)l1 << 16);
  }
}

__global__ void sniff_kernel(const u16* __restrict__ w, int* __restrict__ flag) {
  __shared__ int cnt;
  if (threadIdx.x == 0) cnt = 0;
  __syncthreads();
  int ok = 0;
  for (int i = threadIdx.x; i < 1024; i += 256) {
    u16 u = w[2 * i];
    int e = (u >> 7) & 0xFF;
    ok += (u == 0 || (e >= 97 && e <= 140)) ? 1 : 0;
  }
  atomicAdd(&cnt, ok);
  __syncthreads();
  if (threadIdx.x == 0) *flag = (cnt >= 768) ? 1 : 0;
}

// ---------------- Encoder (both LSTM layers, pipelined) + fused online attention ---
__global__ __launch_bounds__(256, 1) void enc_kernel(
    const void* __restrict__ x,
    const void* __restrict__ eWih0, const void* __restrict__ eWhh0, const void* __restrict__ eb0,
    const void* __restrict__ eWih1, const void* __restrict__ eWhh1, const void* __restrict__ eb1,
    const void* __restrict__ aW, const void* __restrict__ aV,
    u32* __restrict__ H0, u32* __restrict__ H1,
    float* __restrict__ ctx, int* __restrict__ cnt, const int* __restrict__ flagp) {
  __shared__ u16 h0hi[16 * 264], h0lo[16 * 264], h1hi[16 * 264], h1lo[16 * 264]; // 33.8 KB
  __shared__ float gb0[16 * 64], gb1[16 * 64];   // [row][u*4+g]
  __shared__ float eP[16 * 132];                 // attention pre-act [row][a]
  __shared__ float eQ[16 * 17];
  __shared__ float eLs[16];
  __shared__ float aVs[128];

  const int isbf = *flagp;
  const int tid = threadIdx.x, blk = blockIdx.x;
  const int grp = blk & 15, gs = blk >> 4;       // 16 groups x 16 slices
  const int lane = tid & 63, wv = tid >> 6;      // wave = gate index (0..3)
  const int ln = lane & 15, lq = lane >> 4;

  // ---- B-fragments in registers ----
  v8s W0F[9], W1F[16], AWF[16];
  {
    const int gw = wv * 256 + gs * 16 + ln;      // gate row in [4H]
    const int kq = lq * 8;
    W0F[0] = ld8hi(eWih0, (size_t)gw * 32 + kq, isbf);
#pragma unroll
    for (int kt = 0; kt < 8; ++kt) {
      W0F[kt + 1] = ld8hi(eWhh0, (size_t)gw * 256 + kt * 32 + kq, isbf);
      W1F[kt]     = ld8hi(eWhh1, (size_t)gw * 256 + kt * 32 + kq, isbf);
      W1F[kt + 8] = ld8hi(eWih1, (size_t)gw * 256 + kt * 32 + kq, isbf);
    }
#pragma unroll
    for (int kt = 0; kt < 8; ++kt)
#pragma unroll
      for (int j2 = 0; j2 < 2; ++j2) {
        v8s f;
        int ac = (2 * wv + j2) * 16 + ln;        // a-col
#pragma unroll
        for (int j = 0; j < 8; ++j)
          f[j] = (short)f2bf(ldIn(aW, (size_t)(kt * 32 + kq + j) * 128 + ac, isbf));
        AWF[kt * 2 + j2] = f;
      }
  }
  if (tid < 128) aVs[tid] = ldIn(aV, (size_t)tid, isbf);

  const int urow = tid >> 4, uu = tid & 15;
  float bg0[4], bg1[4];
#pragma unroll
  for (int g = 0; g < 4; ++g) {
    bg0[g] = ldIn(eb0, g * 256 + gs * 16 + uu, isbf);
    bg1[g] = ldIn(eb1, g * 256 + gs * 16 + uu, isbf);
  }

  const int gRowU = grp * 16 + urow;
  const int gUnit = gs * 16 + uu;
  const int aRow = grp * 16 + ln;

  float c0 = 0.f, c1 = 0.f;
  float mS = -3e38f, lS = 0.f, ctxA = 0.f;
  int* bcnt = cnt + grp * 32;

  // t: L0 computes h0[t]; L1 computes h1[t-1]; attn+ctx consume h1[t-2]
#pragma unroll 1
  for (int t = 0; t < 514; ++t) {
    const int rB = (t + 1) & 1, wB = t & 1;
    // stage h0[t-1] (parity rB) and h1[t-2] (parity wB)
    stage_u32(h0hi, h0lo, H0 + ((size_t)rB * 256 + grp * 16) * 256, tid);
    stage_u32(h1hi, h1lo, H1 + ((size_t)wB * 256 + grp * 16) * 256, tid);
    __syncthreads();

    v4f acc0 = {0, 0, 0, 0}, acc1 = {0, 0, 0, 0}, accA0 = {0, 0, 0, 0}, accA1 = {0, 0, 0, 0};
    {
      int tt = (t < 512) ? t : 511;
      v8s xh, xl;
      ld8split(x, ((size_t)aRow * 512 + tt) * 32 + lq * 8, isbf, xh, xl);
      acc0 = MFMA(xh, W0F[0], acc0);
      if (!isbf) acc0 = MFMA(xl, W0F[0], acc0);
    }
#pragma unroll
    for (int kt = 0; kt < 8; ++kt) {
      const int off = ln * 264 + kt * 32 + lq * 8;
      v8s a0h = *(const v8s*)(h0hi + off);
      v8s a0l = *(const v8s*)(h0lo + off);
      acc0 = MFMA(a0h, W0F[kt + 1], acc0);
      acc0 = MFMA(a0l, W0F[kt + 1], acc0);
      acc1 = MFMA(a0h, W1F[kt + 8], acc1);      // L1's input-part (h0[t-1])
      acc1 = MFMA(a0l, W1F[kt + 8], acc1);
      v8s a1h = *(const v8s*)(h1hi + off);
      v8s a1l = *(const v8s*)(h1lo + off);
      acc1 = MFMA(a1h, W1F[kt], acc1);          // L1 self (h1[t-2])
      acc1 = MFMA(a1l, W1F[kt], acc1);
      accA0 = MFMA(a1h, AWF[kt * 2], accA0);    // attention on h1[t-2]
      accA0 = MFMA(a1l, AWF[kt * 2], accA0);
      accA1 = MFMA(a1h, AWF[kt * 2 + 1], accA1);
      accA1 = MFMA(a1l, AWF[kt * 2 + 1], accA1);
    }
    {
      const int bR = lq * 4;
#pragma unroll
      for (int r = 0; r < 4; ++r) {
        gb0[(bR + r) * 64 + ln * 4 + wv] = acc0[r];
        gb1[(bR + r) * 64 + ln * 4 + wv] = acc1[r];
        eP[(bR + r) * 132 + (2 * wv) * 16 + ln] = accA0[r];
        eP[(bR + r) * 132 + (2 * wv + 1) * 16 + ln] = accA1[r];
      }
    }
    __syncthreads();
    // updates + attention partial reduce
    if (t < 512) {
      const float* g0 = gb0 + (urow * 16 + uu) * 4;
      float gi = g0[0] + bg0[0], gf = g0[1] + bg0[1], gg = g0[2] + bg0[2], go = g0[3] + bg0[3];
      c0 = sigf(gf) * c0 + sigf(gi) * tanhfast(gg);
      float h = sigf(go) * tanhfast(c0);
      u16 hh = f2bf(h); u16 hl = f2bf(h - bf2f(hh));
      astore32(H0 + ((size_t)wB * 256 + gRowU) * 256 + gUnit, (u32)hh | ((u32)hl << 16));
    }
    if (t >= 1 && t < 513) {
      const float* g1 = gb1 + (urow * 16 + uu) * 4;
      float gi = g1[0] + bg1[0], gf = g1[1] + bg1[1], gg = g1[2] + bg1[2], go = g1[3] + bg1[3];
      c1 = sigf(gf) * c1 + sigf(gi) * tanhfast(gg);
      float h = sigf(go) * tanhfast(c1);
      u16 hh = f2bf(h); u16 hl = f2bf(h - bf2f(hh));
      astore32(H1 + ((size_t)rB * 256 + gRowU) * 256 + gUnit, (u32)hh | ((u32)hl << 16));
    }
    if (t >= 2) {
      float s = 0.f;
#pragma unroll
      for (int j = 0; j < 8; ++j)
        s += tanhfast(eP[urow * 132 + uu * 8 + j]) * aVs[uu * 8 + j];
      eQ[urow * 17 + uu] = s;
    }
    __syncthreads();
    if (t >= 2 && tid < 16) {
      float s = 0.f;
#pragma unroll
      for (int o = 0; o < 16; ++o) s += eQ[tid * 17 + o];
      eLs[tid] = s;
    }
    __syncthreads();
    if (t >= 2) {  // online-softmax ctx accumulation for h1[t-2]
      float e = eLs[urow];
      float h1v = bf2f(h1hi[urow * 264 + gUnit]) + bf2f(h1lo[urow * 264 + gUnit]);
      float nm = fmaxf(mS, e);
      float al = __expf(mS - nm), p = __expf(e - nm);
      lS = lS * al + p;
      ctxA = ctxA * al + p * h1v;
      mS = nm;
    }
    if (t < 513) group_barrier(bcnt, 16 * (t + 1));
  }
  ctx[(size_t)gRowU * 256 + gUnit] = ctxA / lS;
}

// ---------------- Decoder: 24 steps x 2 sub-steps + projection --------------------
__global__ __launch_bounds__(256, 1) void dec_kernel(
    const void* __restrict__ x,
    const void* __restrict__ dWih0, const void* __restrict__ dWhh0, const void* __restrict__ db0,
    const void* __restrict__ dWih1, const void* __restrict__ dWhh1, const void* __restrict__ db1,
    const void* __restrict__ qW, const void* __restrict__ qb,
    const float* __restrict__ ctx,
    u32* __restrict__ H0d, u32* __restrict__ H1d, u32* __restrict__ dinpG,
    void* __restrict__ out, int* __restrict__ cnt, const int* __restrict__ flagp) {
  __shared__ u16 sAhi[16 * 264], sAlo[16 * 264], sBhi[16 * 264], sBlo[16 * 264];
  __shared__ float gb[16 * 64];
  __shared__ float dinpS[16];

  const int isbf = *flagp;
  const int tid = threadIdx.x, blk = blockIdx.x;
  const int grp = blk & 15, gs = blk >> 4;
  const int lane = tid & 63, wv = tid >> 6;
  const int ln = lane & 15, lq = lane >> 4;

  v8s W0F[8], W1F[16];
  {
    const int gw = wv * 256 + gs * 16 + ln;
    const int kq = lq * 8;
#pragma unroll
    for (int kt = 0; kt < 8; ++kt) {
      W0F[kt]     = ld8hi(dWhh0, (size_t)gw * 256 + kt * 32 + kq, isbf);
      W1F[kt]     = ld8hi(dWhh1, (size_t)gw * 256 + kt * 32 + kq, isbf);
      W1F[kt + 8] = ld8hi(dWih1, (size_t)gw * 256 + kt * 32 + kq, isbf);
    }
  }
  const int urow = tid >> 4, uu = tid & 15;
  float bg0[4], bg1[4], w0v[4];
#pragma unroll
  for (int g = 0; g < 4; ++g) {
    bg0[g] = ldIn(db0, g * 256 + gs * 16 + uu, isbf);
    bg1[g] = ldIn(db1, g * 256 + gs * 16 + uu, isbf);
    w0v[g] = ldIn(dWih0, g * 256 + gs * 16 + uu, isbf);
  }
  const int gRowU = grp * 16 + urow;
  const int gUnit = gs * 16 + uu;

  float c0 = ctx[(size_t)gRowU * 256 + gUnit];
  float c1 = c0;
  int* bcnt = cnt + grp * 32;

#pragma unroll 1
  for (int t = 0; t < 24; ++t) {
    const int pPrev = (t + 1) & 1, pCur = t & 1;
    // ---- sub-step A: layer-0 cell ----
    if (t == 0) {
      stage_f32(sAhi, sAlo, ctx + (size_t)grp * 16 * 256, tid);
      if (tid < 16)
        dinpS[tid] = ldIn(x, ((size_t)(grp * 16 + tid) * 512 + 511) * 32 + 31, isbf);
    } else {
      stage_u32(sAhi, sAlo, H0d + ((size_t)pPrev * 256 + grp * 16) * 256, tid);
      if (tid < 16)
        dinpS[tid] = __uint_as_float(aload32(dinpG + pPrev * 256 + grp * 16 + tid));
    }
    __syncthreads();
    v4f acc = {0, 0, 0, 0};
#pragma unroll
    for (int kt = 0; kt < 8; ++kt) {
      const int off = ln * 264 + kt * 32 + lq * 8;
      acc = MFMA(*(const v8s*)(sAhi + off), W0F[kt], acc);
      acc = MFMA(*(const v8s*)(sAlo + off), W0F[kt], acc);
    }
    {
      const int bR = lq * 4;
#pragma unroll
      for (int r = 0; r < 4; ++r) gb[(bR + r) * 64 + ln * 4 + wv] = acc[r];
    }
    __syncthreads();
    {
      float di = dinpS[urow];
      const float* g0 = gb + (urow * 16 + uu) * 4;
      float gi = g0[0] + bg0[0] + di * w0v[0];
      float gf = g0[1] + bg0[1] + di * w0v[1];
      float gg = g0[2] + bg0[2] + di * w0v[2];
      float go = g0[3] + bg0[3] + di * w0v[3];
      c0 = sigf(gf) * c0 + sigf(gi) * tanhfast(gg);
      float h = sigf(go) * tanhfast(c0);
      u16 hh = f2bf(h); u16 hl = f2bf(h - bf2f(hh));
      astore32(H0d + ((size_t)pCur * 256 + gRowU) * 256 + gUnit, (u32)hh | ((u32)hl << 16));
    }
    group_barrier(bcnt, 16 * (2 * t + 1));
    // ---- sub-step B: layer-1 cell ----
    if (t == 0) stage_f32(sBhi, sBlo, ctx + (size_t)grp * 16 * 256, tid);
    else stage_u32(sBhi, sBlo, H1d + ((size_t)pPrev * 256 + grp * 16) * 256, tid);
    stage_u32(sAhi, sAlo, H0d + ((size_t)pCur * 256 + grp * 16) * 256, tid);
    __syncthreads();
    v4f a1 = {0, 0, 0, 0};
#pragma unroll
    for (int kt = 0; kt < 8; ++kt) {
      const int off = ln * 264 + kt * 32 + lq * 8;
      a1 = MFMA(*(const v8s*)(sBhi + off), W1F[kt], a1);       // h1d[t-1]
      a1 = MFMA(*(const v8s*)(sBlo + off), W1F[kt], a1);
      a1 = MFMA(*(const v8s*)(sAhi + off), W1F[kt + 8], a1);   // h0d[t]
      a1 = MFMA(*(const v8s*)(sAlo + off), W1F[kt + 8], a1);
    }
    {
      const int bR = lq * 4;
#pragma unroll
      for (int r = 0; r < 4; ++r) gb[(bR + r) * 64 + ln * 4 + wv] = a1[r];
    }
    __syncthreads();
    {
      const float* g1 = gb + (urow * 16 + uu) * 4;
      float gi = g1[0] + bg1[0], gf = g1[1] + bg1[1], gg = g1[2] + bg1[2], go = g1[3] + bg1[3];
      c1 = sigf(gf) * c1 + sigf(gi) * tanhfast(gg);
      float h = sigf(go) * tanhfast(c1);
      u16 hh = f2bf(h); u16 hl = f2bf(h - bf2f(hh));
      astore32(H1d + ((size_t)pCur * 256 + gRowU) * 256 + gUnit, (u32)hh | ((u32)hl << 16));
      if (gUnit == 0)
        astore32(dinpG + pCur * 256 + gRowU, __float_as_uint(h));
    }
    group_barrier(bcnt, 16 * (2 * t + 2));
  }
  // projection: preds[b][qo] = qb[qo] + sum_h h1d[23][b][h] * qW[qo][h]; h1d[23] parity 1
  if (gs < 12 && tid < 96) {
    int r = tid / 6, p = tid % 6;
    int qo = gs * 6 + p, row = grp * 16 + r;
    const u32* hv = H1d + ((size_t)1 * 256 + row) * 256;
    float s = ldIn(qb, qo, isbf);
    for (int h = 0; h < 256; ++h) {
      u32 w = aload32(hv + h);
      s += (bf2f((u16)w) + bf2f((u16)(w >> 16))) * ldIn(qW, (size_t)qo * 256 + h, isbf);
    }
    if (isbf) ((u16*)out)[row * 72 + qo] = f2bf(s);
    else      ((float*)out)[row * 72 + qo] = s;
  }
}

extern "C" void kernel_launch(void* const* d_in, const int* in_sizes, int n_in,
                              void* d_out, int out_size, void* d_ws, size_t ws_size,
                              hipStream_t stream) {
  const void* x     = d_in[0];
  const void* eWih0 = d_in[1];
  const void* eWhh0 = d_in[2];
  const void* eb0   = d_in[3];
  const void* eWih1 = d_in[4];
  const void* eWhh1 = d_in[5];
  const void* eb1   = d_in[6];
  const void* dWih0 = d_in[7];
  const void* dWhh0 = d_in[8];
  const void* db0   = d_in[9];
  const void* dWih1 = d_in[10];
  const void* dWhh1 = d_in[11];
  const void* db1   = d_in[12];
  const void* aW    = d_in[13];
  const void* aV    = d_in[14];
  const void* qW    = d_in[15];
  const void* qb    = d_in[16];

  char* wsb = (char*)d_ws;
  u32*   H0    = (u32*)(wsb + 0);              // [2][256][256] u32 = 524288 B
  u32*   H1    = (u32*)(wsb + 524288);         // 524288
  int*   cntE  = (int*)(wsb + 1048576);        // 16 groups x 32 ints = 2048
  int*   cntD  = (int*)(wsb + 1050624);        // 2048
  int*   flag  = (int*)(wsb + 1052672);        // 256
  u32*   dinpG = (u32*)(wsb + 1052928);        // [2][256] = 2048
  float* ctx   = (float*)(wsb + 1056768);      // 262144
  u32*   H0d   = (u32*)(wsb + 1318912);        // 524288
  u32*   H1d   = (u32*)(wsb + 1843200);        // 524288
  // total ws: 2,367,488 bytes

  hipMemsetAsync(wsb, 0, 1054976, stream);     // H0, H1, counters, flag

  sniff_kernel<<<1, 256, 0, stream>>>((const u16*)eWhh0, flag);
  enc_kernel<<<256, 256, 0, stream>>>(x, eWih0, eWhh0, eb0, eWih1, eWhh1, eb1,
                                      aW, aV, H0, H1, ctx, cntE, flag);
  dec_kernel<<<256, 256, 0, stream>>>(x, dWih0, dWhh0, db0, dWih1, dWhh1, db1,
                                      qW, qb, ctx, H0d, H1d, dinpG,
                                      d_out, cntD, flag);
}

// Round 4
// 3242.074 us; speedup vs baseline: 3.4132x; 1.0045x over previous
//
#include <hip/hip_runtime.h>

typedef unsigned short u16;
typedef unsigned int u32;
typedef unsigned long long u64;
typedef short v8s __attribute__((ext_vector_type(8)));
typedef float v4f __attribute__((ext_vector_type(4)));

// Dims: B=256, T=512, D=32, H=256, 4H=1024, A=128, HOR=24, NQ=3
// 256 blocks = 16 groups (16 batch rows) x 16 slices (16 units = 64 gate-cols).
// Weights in registers as MFMA B-frags. Encoder h exchanged hi-only (bf16) as
// raw u64 quads; c-state fp32 in registers. Decoder keeps hi/lo (24 steps only).
// Exchange via relaxed agent atomics (no fences -> no L2 writeback storms).

__device__ __forceinline__ float bf2f(u16 u) { union { u32 u; float f; } c; c.u = ((u32)u) << 16; return c.f; }
__device__ __forceinline__ u16 f2bf(float f) {
  union { float f; u32 u; } c; c.f = f;
  u32 r = c.u + 0x7FFFu + ((c.u >> 16) & 1u);   // RTNE
  return (u16)(r >> 16);
}
__device__ __forceinline__ float sigf(float x) { return 1.f / (1.f + __expf(-x)); }
__device__ __forceinline__ float tanhfast(float x) {
  x = fminf(15.f, fmaxf(-15.f, x));
  float e = __expf(2.f * x);
  return (e - 1.f) / (e + 1.f);
}
__device__ __forceinline__ float ldIn(const void* p, size_t i, int isbf) {
  return isbf ? bf2f(((const u16*)p)[i]) : ((const float*)p)[i];
}
__device__ __forceinline__ v8s ld8hi(const void* p, size_t e, int isbf) {
  if (isbf) return *(const v8s*)((const u16*)p + e);
  const float* f = (const float*)p + e;
  v8s r;
#pragma unroll
  for (int j = 0; j < 8; ++j) r[j] = (short)f2bf(f[j]);
  return r;
}
__device__ __forceinline__ void ld8split(const void* p, size_t e, int isbf, v8s& hi, v8s& lo) {
  if (isbf) {
    hi = *(const v8s*)((const u16*)p + e);
    lo = v8s{0, 0, 0, 0, 0, 0, 0, 0};
  } else {
    const float* f = (const float*)p + e;
#pragma unroll
    for (int j = 0; j < 8; ++j) {
      u16 h = f2bf(f[j]);
      hi[j] = (short)h;
      lo[j] = (short)f2bf(f[j] - bf2f(h));
    }
  }
}
#define MFMA(a, b, c) __builtin_amdgcn_mfma_f32_16x16x32_bf16(a, b, c, 0, 0, 0)

__device__ __forceinline__ u64 aload64(const u64* p) {
  return __hip_atomic_load(p, __ATOMIC_RELAXED, __HIP_MEMORY_SCOPE_AGENT);
}
__device__ __forceinline__ u32 aload32(const u32* p) {
  return __hip_atomic_load(p, __ATOMIC_RELAXED, __HIP_MEMORY_SCOPE_AGENT);
}
__device__ __forceinline__ void astore32(u32* p, u32 v) {
  __hip_atomic_store(p, v, __ATOMIC_RELAXED, __HIP_MEMORY_SCOPE_AGENT);
}
__device__ __forceinline__ void astore16(u16* p, u16 v) {
  __hip_atomic_store(p, v, __ATOMIC_RELAXED, __HIP_MEMORY_SCOPE_AGENT);
}

// Group barrier: leader adds after __syncthreads (which drains all waves' vmcnt,
// so every store of the block reached the coherence point); ALL threads poll
// (no trailing sync / no leader->block handoff). The internal __syncthreads also
// protects LDS staging-buffer reuse across iterations.
__device__ __forceinline__ void group_barrier(int* cnt, int expected) {
  __syncthreads();
  if (threadIdx.x == 0)
    __hip_atomic_fetch_add(cnt, 1, __ATOMIC_RELAXED, __HIP_MEMORY_SCOPE_AGENT);
  while (__hip_atomic_load(cnt, __ATOMIC_RELAXED, __HIP_MEMORY_SCOPE_AGENT) < expected) {}
}

// Stage 16 rows x 256 bf16 units (u16) into LDS rows of stride 264 u16.
__device__ __forceinline__ void stage16(u16* dst, const u16* src, int tid) {
  const u64* s = (const u64*)src;
#pragma unroll
  for (int i = 0; i < 4; ++i) {
    int w = i * 256 + tid;                 // u64 index in [16][64]
    int row = w >> 6, c8 = w & 63;
    u64 v = aload64(s + w);
    *(u64*)(dst + row * 264 + c8 * 4) = v;
  }
}
// Decoder staging (u32-packed hi|lo) -> de-interleaved hi/lo LDS.
__device__ __forceinline__ void stage_u32(u16* dhi, u16* dlo, const u32* src, int tid) {
  const u64* s = (const u64*)src;
#pragma unroll
  for (int i = 0; i < 4; ++i) {
    int base = i * 512 + tid * 2;
    int row = base >> 7, jp = base & 127;
    u64 wa = aload64(s + row * 128 + jp);
    u64 wb = aload64(s + row * 128 + jp + 1);
    u32 a0 = (u32)wa, a1 = (u32)(wa >> 32), b0 = (u32)wb, b1 = (u32)(wb >> 32);
    u32 hp0 = (a0 & 0xFFFFu) | (a1 << 16), lp0 = (a0 >> 16) | (a1 & 0xFFFF0000u);
    u32 hp1 = (b0 & 0xFFFFu) | (b1 << 16), lp1 = (b0 >> 16) | (b1 & 0xFFFF0000u);
    *(u64*)((u32*)(dhi + row * 264) + jp) = ((u64)hp1 << 32) | hp0;
    *(u64*)((u32*)(dlo + row * 264) + jp) = ((u64)lp1 << 32) | lp0;
  }
}
__device__ __forceinline__ void stage_f32(u16* dhi, u16* dlo, const float* src, int tid) {
#pragma unroll
  for (int i = 0; i < 8; ++i) {
    int e = i * 512 + tid * 2;
    int row = e >> 8, jc = e & 255;
    float f0 = src[row * 256 + jc], f1 = src[row * 256 + jc + 1];
    u16 h0 = f2bf(f0), h1 = f2bf(f1);
    u16 l0 = f2bf(f0 - bf2f(h0)), l1 = f2bf(f1 - bf2f(h1));
    ((u32*)(dhi + row * 264))[jc >> 1] = (u32)h0 | ((u32)h1 << 16);
    ((u32*)(dlo + row * 264))[jc >> 1] = (u32)l0 | ((u32)l1 << 16);
  }
}

__global__ void sniff_kernel(const u16* __restrict__ w, int* __restrict__ flag) {
  __shared__ int cnt;
  if (threadIdx.x == 0) cnt = 0;
  __syncthreads();
  int ok = 0;
  for (int i = threadIdx.x; i < 1024; i += 256) {
    u16 u = w[2 * i];
    int e = (u >> 7) & 0xFF;
    ok += (u == 0 || (e >= 97 && e <= 140)) ? 1 : 0;
  }
  atomicAdd(&cnt, ok);
  __syncthreads();
  if (threadIdx.x == 0) *flag = (cnt >= 768) ? 1 : 0;
}

// ---------------- Encoder (both LSTM layers, pipelined) + fused online attention ---
__global__ __launch_bounds__(256, 1) void enc_kernel(
    const void* __restrict__ x,
    const void* __restrict__ eWih0, const void* __restrict__ eWhh0, const void* __restrict__ eb0,
    const void* __restrict__ eWih1, const void* __restrict__ eWhh1, const void* __restrict__ eb1,
    const void* __restrict__ aW, const void* __restrict__ aV,
    u16* __restrict__ H0, u16* __restrict__ H1,
    float* __restrict__ ctx, int* __restrict__ cnt, const int* __restrict__ flagp) {
  __shared__ u16 h0s[16 * 264], h1s[16 * 264];   // 16.5 KB
  __shared__ float gb0[16 * 64], gb1[16 * 64];   // [row][unit*4+gate]
  __shared__ float eP[16 * 132];                 // attention pre-act [row][a]

  const int isbf = *flagp;
  const int tid = threadIdx.x, blk = blockIdx.x;
  const int grp = blk & 15, gs = blk >> 4;
  const int lane = tid & 63, wv = tid >> 6;      // wave = gate index
  const int ln = lane & 15, lq = lane >> 4;

  // B-fragments in registers
  v8s W0F[9], W1F[16], AWF[16];
  {
    const int gw = wv * 256 + gs * 16 + ln;
    const int kq = lq * 8;
    W0F[0] = ld8hi(eWih0, (size_t)gw * 32 + kq, isbf);
#pragma unroll
    for (int kt = 0; kt < 8; ++kt) {
      W0F[kt + 1] = ld8hi(eWhh0, (size_t)gw * 256 + kt * 32 + kq, isbf);
      W1F[kt]     = ld8hi(eWhh1, (size_t)gw * 256 + kt * 32 + kq, isbf);
      W1F[kt + 8] = ld8hi(eWih1, (size_t)gw * 256 + kt * 32 + kq, isbf);
    }
#pragma unroll
    for (int kt = 0; kt < 8; ++kt)
#pragma unroll
      for (int j2 = 0; j2 < 2; ++j2) {
        v8s f;
        int ac = (2 * wv + j2) * 16 + ln;
#pragma unroll
        for (int j = 0; j < 8; ++j)
          f[j] = (short)f2bf(ldIn(aW, (size_t)(kt * 32 + kq + j) * 128 + ac, isbf));
        AWF[kt * 2 + j2] = f;
      }
  }

  const int urow = tid >> 4, uu = tid & 15;
  float bg0[4], bg1[4], aVr[8];
#pragma unroll
  for (int g = 0; g < 4; ++g) {
    bg0[g] = ldIn(eb0, g * 256 + gs * 16 + uu, isbf);
    bg1[g] = ldIn(eb1, g * 256 + gs * 16 + uu, isbf);
  }
#pragma unroll
  for (int j = 0; j < 8; ++j) aVr[j] = ldIn(aV, (size_t)(uu + 16 * j), isbf);

  const int gRowU = grp * 16 + urow;
  const int gUnit = gs * 16 + uu;
  const int aRow = grp * 16 + ln;

  float c0 = 0.f, c1 = 0.f;
  float mS = -3e38f, lS = 0.f, ctxA = 0.f;
  float h_d1 = 0.f;
  int* bcnt = cnt + grp * 32;

  v8s xh_c, xl_c;
  ld8split(x, ((size_t)aRow * 512) * 32 + lq * 8, isbf, xh_c, xl_c);

  // t: L0 -> h0[t]; L1 -> h1[t-1]; attn+ctx consume h1[t-2]
#pragma unroll 1
  for (int t = 0; t < 514; ++t) {
    const int rB = (t + 1) & 1, wB = t & 1;
    stage16(h0s, H0 + ((size_t)rB * 256 + grp * 16) * 256, tid);   // h0[t-1]
    stage16(h1s, H1 + ((size_t)wB * 256 + grp * 16) * 256, tid);   // h1[t-2]
    // prefetch x for next step (consumed next iteration; latency hidden)
    v8s xh_n, xl_n;
    {
      int tn = (t + 1 < 512) ? t + 1 : 511;
      ld8split(x, ((size_t)aRow * 512 + tn) * 32 + lq * 8, isbf, xh_n, xl_n);
    }
    __syncthreads();

    v4f acc0 = {0, 0, 0, 0}, acc1 = {0, 0, 0, 0}, accA0 = {0, 0, 0, 0}, accA1 = {0, 0, 0, 0};
    acc0 = MFMA(xh_c, W0F[0], acc0);
    if (!isbf) acc0 = MFMA(xl_c, W0F[0], acc0);
#pragma unroll
    for (int kt = 0; kt < 8; ++kt) {
      const int off = ln * 264 + kt * 32 + lq * 8;
      v8s a0 = *(const v8s*)(h0s + off);
      acc0 = MFMA(a0, W0F[kt + 1], acc0);
      acc1 = MFMA(a0, W1F[kt + 8], acc1);       // L1 input-part (h0[t-1])
      v8s a1 = *(const v8s*)(h1s + off);
      acc1 = MFMA(a1, W1F[kt], acc1);           // L1 self (h1[t-2])
      accA0 = MFMA(a1, AWF[kt * 2], accA0);     // attention on h1[t-2]
      accA1 = MFMA(a1, AWF[kt * 2 + 1], accA1);
    }
    {
      const int bR = lq * 4;
#pragma unroll
      for (int r = 0; r < 4; ++r) {
        gb0[(bR + r) * 64 + ln * 4 + wv] = acc0[r];
        gb1[(bR + r) * 64 + ln * 4 + wv] = acc1[r];
        eP[(bR + r) * 132 + (2 * wv) * 16 + ln] = accA0[r];
        eP[(bR + r) * 132 + (2 * wv + 1) * 16 + ln] = accA1[r];
      }
    }
    __syncthreads();
    // L0 update
    if (t < 512) {
      const float* g0 = gb0 + (urow * 16 + uu) * 4;
      float gi = g0[0] + bg0[0], gf = g0[1] + bg0[1], gg = g0[2] + bg0[2], go = g0[3] + bg0[3];
      c0 = sigf(gf) * c0 + sigf(gi) * tanhfast(gg);
      float h = sigf(go) * tanhfast(c0);
      astore16(H0 + ((size_t)wB * 256 + gRowU) * 256 + gUnit, f2bf(h));
    }
    // L1 update
    float hnew = h_d1;
    if (t >= 1 && t < 513) {
      const float* g1 = gb1 + (urow * 16 + uu) * 4;
      float gi = g1[0] + bg1[0], gf = g1[1] + bg1[1], gg = g1[2] + bg1[2], go = g1[3] + bg1[3];
      c1 = sigf(gf) * c1 + sigf(gi) * tanhfast(gg);
      float h = sigf(go) * tanhfast(c1);
      astore16(H1 + ((size_t)rB * 256 + gRowU) * 256 + gUnit, f2bf(h));
      hnew = h;
    }
    // e[row] for h1[t-2] via in-wave shuffle reduce (lanes of a row are contiguous)
    if (t >= 2) {
      float e = 0.f;
#pragma unroll
      for (int j = 0; j < 8; ++j)
        e += tanhfast(eP[urow * 132 + uu + 16 * j]) * aVr[j];
      e += __shfl_xor(e, 1);
      e += __shfl_xor(e, 2);
      e += __shfl_xor(e, 4);
      e += __shfl_xor(e, 8);
      // online-softmax ctx accumulation with h1[t-2] from LDS
      float h1v = bf2f(h1s[urow * 264 + gUnit]);
      float nm = fmaxf(mS, e);
      float al = __expf(mS - nm), p = __expf(e - nm);
      lS = lS * al + p;
      ctxA = ctxA * al + p * h1v;
      mS = nm;
    }
    h_d1 = hnew;
    xh_c = xh_n; xl_c = xl_n;
    if (t < 513) group_barrier(bcnt, 16 * (t + 1));
  }
  ctx[(size_t)gRowU * 256 + gUnit] = ctxA / lS;
}

// ---------------- Decoder: 24 steps x 2 sub-steps + projection (hi/lo kept) -------
__global__ __launch_bounds__(256, 1) void dec_kernel(
    const void* __restrict__ x,
    const void* __restrict__ dWih0, const void* __restrict__ dWhh0, const void* __restrict__ db0,
    const void* __restrict__ dWih1, const void* __restrict__ dWhh1, const void* __restrict__ db1,
    const void* __restrict__ qW, const void* __restrict__ qb,
    const float* __restrict__ ctx,
    u32* __restrict__ H0d, u32* __restrict__ H1d, u32* __restrict__ dinpG,
    void* __restrict__ out, int* __restrict__ cnt, const int* __restrict__ flagp) {
  __shared__ u16 sAhi[16 * 264], sAlo[16 * 264], sBhi[16 * 264], sBlo[16 * 264];
  __shared__ float gb[16 * 64];
  __shared__ float dinpS[16];

  const int isbf = *flagp;
  const int tid = threadIdx.x, blk = blockIdx.x;
  const int grp = blk & 15, gs = blk >> 4;
  const int lane = tid & 63, wv = tid >> 6;
  const int ln = lane & 15, lq = lane >> 4;

  v8s W0F[8], W1F[16];
  {
    const int gw = wv * 256 + gs * 16 + ln;
    const int kq = lq * 8;
#pragma unroll
    for (int kt = 0; kt < 8; ++kt) {
      W0F[kt]     = ld8hi(dWhh0, (size_t)gw * 256 + kt * 32 + kq, isbf);
      W1F[kt]     = ld8hi(dWhh1, (size_t)gw * 256 + kt * 32 + kq, isbf);
      W1F[kt + 8] = ld8hi(dWih1, (size_t)gw * 256 + kt * 32 + kq, isbf);
    }
  }
  const int urow = tid >> 4, uu = tid & 15;
  float bg0[4], bg1[4], w0v[4];
#pragma unroll
  for (int g = 0; g < 4; ++g) {
    bg0[g] = ldIn(db0, g * 256 + gs * 16 + uu, isbf);
    bg1[g] = ldIn(db1, g * 256 + gs * 16 + uu, isbf);
    w0v[g] = ldIn(dWih0, g * 256 + gs * 16 + uu, isbf);
  }
  const int gRowU = grp * 16 + urow;
  const int gUnit = gs * 16 + uu;

  float c0 = ctx[(size_t)gRowU * 256 + gUnit];
  float c1 = c0;
  int* bcnt = cnt + grp * 32;

  __syncthreads();

#pragma unroll 1
  for (int t = 0; t < 24; ++t) {
    const int pPrev = (t + 1) & 1, pCur = t & 1;
    // ---- sub-step A: layer-0 cell ----
    if (t == 0) {
      stage_f32(sAhi, sAlo, ctx + (size_t)grp * 16 * 256, tid);
      if (tid < 16)
        dinpS[tid] = ldIn(x, ((size_t)(grp * 16 + tid) * 512 + 511) * 32 + 31, isbf);
    } else {
      stage_u32(sAhi, sAlo, H0d + ((size_t)pPrev * 256 + grp * 16) * 256, tid);
      if (tid < 16)
        dinpS[tid] = __uint_as_float(aload32(dinpG + pPrev * 256 + grp * 16 + tid));
    }
    __syncthreads();
    v4f acc = {0, 0, 0, 0};
#pragma unroll
    for (int kt = 0; kt < 8; ++kt) {
      const int off = ln * 264 + kt * 32 + lq * 8;
      acc = MFMA(*(const v8s*)(sAhi + off), W0F[kt], acc);
      acc = MFMA(*(const v8s*)(sAlo + off), W0F[kt], acc);
    }
    {
      const int bR = lq * 4;
#pragma unroll
      for (int r = 0; r < 4; ++r) gb[(bR + r) * 64 + ln * 4 + wv] = acc[r];
    }
    __syncthreads();
    {
      float di = dinpS[urow];
      const float* g0 = gb + (urow * 16 + uu) * 4;
      float gi = g0[0] + bg0[0] + di * w0v[0];
      float gf = g0[1] + bg0[1] + di * w0v[1];
      float gg = g0[2] + bg0[2] + di * w0v[2];
      float go = g0[3] + bg0[3] + di * w0v[3];
      c0 = sigf(gf) * c0 + sigf(gi) * tanhfast(gg);
      float h = sigf(go) * tanhfast(c0);
      u16 hh = f2bf(h); u16 hl = f2bf(h - bf2f(hh));
      astore32(H0d + ((size_t)pCur * 256 + gRowU) * 256 + gUnit, (u32)hh | ((u32)hl << 16));
    }
    group_barrier(bcnt, 16 * (2 * t + 1));
    // ---- sub-step B: layer-1 cell ----
    if (t == 0) stage_f32(sBhi, sBlo, ctx + (size_t)grp * 16 * 256, tid);
    else stage_u32(sBhi, sBlo, H1d + ((size_t)pPrev * 256 + grp * 16) * 256, tid);
    stage_u32(sAhi, sAlo, H0d + ((size_t)pCur * 256 + grp * 16) * 256, tid);
    __syncthreads();
    v4f a1 = {0, 0, 0, 0};
#pragma unroll
    for (int kt = 0; kt < 8; ++kt) {
      const int off = ln * 264 + kt * 32 + lq * 8;
      a1 = MFMA(*(const v8s*)(sBhi + off), W1F[kt], a1);       // h1d[t-1]
      a1 = MFMA(*(const v8s*)(sBlo + off), W1F[kt], a1);
      a1 = MFMA(*(const v8s*)(sAhi + off), W1F[kt + 8], a1);   // h0d[t]
      a1 = MFMA(*(const v8s*)(sAlo + off), W1F[kt + 8], a1);
    }
    {
      const int bR = lq * 4;
#pragma unroll
      for (int r = 0; r < 4; ++r) gb[(bR + r) * 64 + ln * 4 + wv] = a1[r];
    }
    __syncthreads();
    {
      const float* g1 = gb + (urow * 16 + uu) * 4;
      float gi = g1[0] + bg1[0], gf = g1[1] + bg1[1], gg = g1[2] + bg1[2], go = g1[3] + bg1[3];
      c1 = sigf(gf) * c1 + sigf(gi) * tanhfast(gg);
      float h = sigf(go) * tanhfast(c1);
      u16 hh = f2bf(h); u16 hl = f2bf(h - bf2f(hh));
      astore32(H1d + ((size_t)pCur * 256 + gRowU) * 256 + gUnit, (u32)hh | ((u32)hl << 16));
      if (gUnit == 0)
        astore32(dinpG + pCur * 256 + gRowU, __float_as_uint(h));
    }
    group_barrier(bcnt, 16 * (2 * t + 2));
  }
  // projection: preds[b][qo] = qb[qo] + sum_h h1d[23][b][h] * qW[qo][h]; parity 1
  if (gs < 12 && tid < 96) {
    int r = tid / 6, p = tid % 6;
    int qo = gs * 6 + p, row = grp * 16 + r;
    const u32* hv = H1d + ((size_t)1 * 256 + row) * 256;
    float s = ldIn(qb, qo, isbf);
    for (int h = 0; h < 256; ++h) {
      u32 w = aload32(hv + h);
      s += (bf2f((u16)w) + bf2f((u16)(w >> 16))) * ldIn(qW, (size_t)qo * 256 + h, isbf);
    }
    if (isbf) ((u16*)out)[row * 72 + qo] = f2bf(s);
    else      ((float*)out)[row * 72 + qo] = s;
  }
}

extern "C" void kernel_launch(void* const* d_in, const int* in_sizes, int n_in,
                              void* d_out, int out_size, void* d_ws, size_t ws_size,
                              hipStream_t stream) {
  const void* x     = d_in[0];
  const void* eWih0 = d_in[1];
  const void* eWhh0 = d_in[2];
  const void* eb0   = d_in[3];
  const void* eWih1 = d_in[4];
  const void* eWhh1 = d_in[5];
  const void* eb1   = d_in[6];
  const void* dWih0 = d_in[7];
  const void* dWhh0 = d_in[8];
  const void* db0   = d_in[9];
  const void* dWih1 = d_in[10];
  const void* dWhh1 = d_in[11];
  const void* db1   = d_in[12];
  const void* aW    = d_in[13];
  const void* aV    = d_in[14];
  const void* qW    = d_in[15];
  const void* qb    = d_in[16];

  char* wsb = (char*)d_ws;
  u16*   H0    = (u16*)(wsb + 0);              // [2][256][256] u16 = 262144 B
  u16*   H1    = (u16*)(wsb + 262144);         // 262144
  int*   cntE  = (int*)(wsb + 524288);         // 2048
  int*   cntD  = (int*)(wsb + 526336);         // 2048
  int*   flag  = (int*)(wsb + 528384);         // 256
  u32*   dinpG = (u32*)(wsb + 528640);         // 2048
  float* ctx   = (float*)(wsb + 530688);       // 262144
  u32*   H0d   = (u32*)(wsb + 792832);         // 524288
  u32*   H1d   = (u32*)(wsb + 1317120);        // 524288
  // total ws: 1,841,408 bytes

  hipMemsetAsync(wsb, 0, 530688, stream);      // H0, H1, counters, flag, dinpG

  sniff_kernel<<<1, 256, 0, stream>>>((const u16*)eWhh0, flag);
  enc_kernel<<<256, 256, 0, stream>>>(x, eWih0, eWhh0, eb0, eWih1, eWhh1, eb1,
                                      aW, aV, H0, H1, ctx, cntE, flag);
  dec_kernel<<<256, 256, 0, stream>>>(x, dWih0, dWhh0, db0, dWih1, dWhh1, db1,
                                      qW, qb, ctx, H0d, H1d, dinpG,
                                      d_out, cntD, flag);
}

// Round 5
// 2303.884 us; speedup vs baseline: 4.8032x; 1.4072x over previous
//
#include <hip/hip_runtime.h>

typedef unsigned short u16;
typedef unsigned int u32;
typedef unsigned long long u64;
typedef short v8s __attribute__((ext_vector_type(8)));
typedef float v4f __attribute__((ext_vector_type(4)));

// Dims: B=256, T=512, D=32, H=256, 4H=1024, A=128, HOR=24, NQ=3
// 256 blocks = 16 groups (16 batch rows) x 16 slices (16 units = 64 gate-cols).
// Weights in registers as MFMA B-frags. NO barrier: h exchanged as tag-embedded
// words (value | step_tag). Readers spin on stale tags only -> one-way latency,
// no hot counter line. Relaxed agent atomics throughout (no fences).

__device__ __forceinline__ float bf2f(u16 u) { union { u32 u; float f; } c; c.u = ((u32)u) << 16; return c.f; }
__device__ __forceinline__ u16 f2bf(float f) {
  union { float f; u32 u; } c; c.f = f;
  u32 r = c.u + 0x7FFFu + ((c.u >> 16) & 1u);   // RTNE
  return (u16)(r >> 16);
}
__device__ __forceinline__ float sigf(float x) { return 1.f / (1.f + __expf(-x)); }
__device__ __forceinline__ float tanhfast(float x) {
  x = fminf(15.f, fmaxf(-15.f, x));
  float e = __expf(2.f * x);
  return (e - 1.f) / (e + 1.f);
}
__device__ __forceinline__ float ldIn(const void* p, size_t i, int isbf) {
  return isbf ? bf2f(((const u16*)p)[i]) : ((const float*)p)[i];
}
__device__ __forceinline__ v8s ld8hi(const void* p, size_t e, int isbf) {
  if (isbf) return *(const v8s*)((const u16*)p + e);
  const float* f = (const float*)p + e;
  v8s r;
#pragma unroll
  for (int j = 0; j < 8; ++j) r[j] = (short)f2bf(f[j]);
  return r;
}
__device__ __forceinline__ void ld8split(const void* p, size_t e, int isbf, v8s& hi, v8s& lo) {
  if (isbf) {
    hi = *(const v8s*)((const u16*)p + e);
    lo = v8s{0, 0, 0, 0, 0, 0, 0, 0};
  } else {
    const float* f = (const float*)p + e;
#pragma unroll
    for (int j = 0; j < 8; ++j) {
      u16 h = f2bf(f[j]);
      hi[j] = (short)h;
      lo[j] = (short)f2bf(f[j] - bf2f(h));
    }
  }
}
#define MFMA(a, b, c) __builtin_amdgcn_mfma_f32_16x16x32_bf16(a, b, c, 0, 0, 0)

__device__ __forceinline__ u64 aload64(const u64* p) {
  return __hip_atomic_load(p, __ATOMIC_RELAXED, __HIP_MEMORY_SCOPE_AGENT);
}
__device__ __forceinline__ void astore32(u32* p, u32 v) {
  __hip_atomic_store(p, v, __ATOMIC_RELAXED, __HIP_MEMORY_SCOPE_AGENT);
}
__device__ __forceinline__ void astore64(u64* p, u64 v) {
  __hip_atomic_store(p, v, __ATOMIC_RELAXED, __HIP_MEMORY_SCOPE_AGENT);
}

// ---- Encoder combined tagged stage: h0 (optional) + h1, u32 words (bf16|tag<<16)
// src arrays are [16 rows][256 units] u32 viewed as [16][128] u64 (2 units/u64).
__device__ __forceinline__ void stage_enc(u16* h0s, u16* h1s,
                                          const u32* s0, const u32* s1,
                                          int tid, u32 tag, bool doH0) {
  const u64* p0 = (const u64*)s0;
  const u64* p1 = (const u64*)s1;
  u64 v0[8], v1[8];
#pragma unroll
  for (int i = 0; i < 8; ++i) {
    if (doH0) v0[i] = aload64(p0 + i * 256 + tid);
    v1[i] = aload64(p1 + i * 256 + tid);
  }
  bool all;
  do {
    all = true;
#pragma unroll
    for (int i = 0; i < 8; ++i) {
      if (doH0) {
        u64 w = v0[i];
        if (!((((w >> 16) & 0xFFFFull) == tag) && ((w >> 48) == tag))) {
          all = false;
          v0[i] = aload64(p0 + i * 256 + tid);
        }
      }
      u64 w1 = v1[i];
      if (!((((w1 >> 16) & 0xFFFFull) == tag) && ((w1 >> 48) == tag))) {
        all = false;
        v1[i] = aload64(p1 + i * 256 + tid);
      }
    }
  } while (!all);
#pragma unroll
  for (int i = 0; i < 8; ++i) {
    int idx = i * 256 + tid;
    int row = idx >> 7, jp = idx & 127;   // u64 col -> units 2jp, 2jp+1
    if (doH0) {
      u64 w = v0[i];
      ((u32*)(h0s + row * 264))[jp] = (u32)(w & 0xFFFF) | (((u32)(w >> 32) & 0xFFFF) << 16);
    }
    u64 w = v1[i];
    ((u32*)(h1s + row * 264))[jp] = (u32)(w & 0xFFFF) | (((u32)(w >> 32) & 0xFFFF) << 16);
  }
}

// ---- Decoder tagged stage: u64/unit = hi | lo<<16 | tag<<32, [16][256] u64.
__device__ __forceinline__ void stage_dec(u16* dhi, u16* dlo, const u64* src,
                                          int tid, u32 tag) {
  u64 v[16];
#pragma unroll
  for (int i = 0; i < 16; ++i) v[i] = aload64(src + i * 256 + tid);
  bool all;
  do {
    all = true;
#pragma unroll
    for (int i = 0; i < 16; ++i) {
      if ((u32)(v[i] >> 32) != tag) { all = false; v[i] = aload64(src + i * 256 + tid); }
    }
  } while (!all);
#pragma unroll
  for (int i = 0; i < 16; ++i) {
    int idx = i * 256 + tid;
    int row = idx >> 8, col = idx & 255;
    dhi[row * 264 + col] = (u16)v[i];
    dlo[row * 264 + col] = (u16)(v[i] >> 16);
  }
}
__device__ __forceinline__ void stage_f32(u16* dhi, u16* dlo, const float* src, int tid) {
#pragma unroll
  for (int i = 0; i < 8; ++i) {
    int e = i * 512 + tid * 2;
    int row = e >> 8, jc = e & 255;
    float f0 = src[row * 256 + jc], f1 = src[row * 256 + jc + 1];
    u16 h0 = f2bf(f0), h1 = f2bf(f1);
    u16 l0 = f2bf(f0 - bf2f(h0)), l1 = f2bf(f1 - bf2f(h1));
    ((u32*)(dhi + row * 264))[jc >> 1] = (u32)h0 | ((u32)h1 << 16);
    ((u32*)(dlo + row * 264))[jc >> 1] = (u32)l0 | ((u32)l1 << 16);
  }
}

__global__ void sniff_kernel(const u16* __restrict__ w, int* __restrict__ flag) {
  __shared__ int cnt;
  if (threadIdx.x == 0) cnt = 0;
  __syncthreads();
  int ok = 0;
  for (int i = threadIdx.x; i < 1024; i += 256) {
    u16 u = w[2 * i];
    int e = (u >> 7) & 0xFF;
    ok += (u == 0 || (e >= 97 && e <= 140)) ? 1 : 0;
  }
  atomicAdd(&cnt, ok);
  __syncthreads();
  if (threadIdx.x == 0) *flag = (cnt >= 768) ? 1 : 0;
}

// ---------------- Encoder (both LSTM layers, pipelined) + fused online attention ---
__global__ __launch_bounds__(256, 1) void enc_kernel(
    const void* __restrict__ x,
    const void* __restrict__ eWih0, const void* __restrict__ eWhh0, const void* __restrict__ eb0,
    const void* __restrict__ eWih1, const void* __restrict__ eWhh1, const void* __restrict__ eb1,
    const void* __restrict__ aW, const void* __restrict__ aV,
    u32* __restrict__ H0, u32* __restrict__ H1,
    float* __restrict__ ctx, const int* __restrict__ flagp) {
  __shared__ u16 h0s[16 * 264], h1s[16 * 264];
  __shared__ float gb0[16 * 64], gb1[16 * 64];
  __shared__ float eP[16 * 132];

  const int isbf = *flagp;
  const int tid = threadIdx.x, blk = blockIdx.x;
  const int grp = blk & 15, gs = blk >> 4;
  const int lane = tid & 63, wv = tid >> 6;      // wave = gate index
  const int ln = lane & 15, lq = lane >> 4;

  v8s W0F[9], W1F[16], AWF[16];
  {
    const int gw = wv * 256 + gs * 16 + ln;
    const int kq = lq * 8;
    W0F[0] = ld8hi(eWih0, (size_t)gw * 32 + kq, isbf);
#pragma unroll
    for (int kt = 0; kt < 8; ++kt) {
      W0F[kt + 1] = ld8hi(eWhh0, (size_t)gw * 256 + kt * 32 + kq, isbf);
      W1F[kt]     = ld8hi(eWhh1, (size_t)gw * 256 + kt * 32 + kq, isbf);
      W1F[kt + 8] = ld8hi(eWih1, (size_t)gw * 256 + kt * 32 + kq, isbf);
    }
#pragma unroll
    for (int kt = 0; kt < 8; ++kt)
#pragma unroll
      for (int j2 = 0; j2 < 2; ++j2) {
        v8s f;
        int ac = (2 * wv + j2) * 16 + ln;
#pragma unroll
        for (int j = 0; j < 8; ++j)
          f[j] = (short)f2bf(ldIn(aW, (size_t)(kt * 32 + kq + j) * 128 + ac, isbf));
        AWF[kt * 2 + j2] = f;
      }
  }

  const int urow = tid >> 4, uu = tid & 15;
  float bg0[4], bg1[4], aVr[8];
#pragma unroll
  for (int g = 0; g < 4; ++g) {
    bg0[g] = ldIn(eb0, g * 256 + gs * 16 + uu, isbf);
    bg1[g] = ldIn(eb1, g * 256 + gs * 16 + uu, isbf);
  }
#pragma unroll
  for (int j = 0; j < 8; ++j) aVr[j] = ldIn(aV, (size_t)(uu + 16 * j), isbf);

  const int gRowU = grp * 16 + urow;
  const int gUnit = gs * 16 + uu;
  const int aRow = grp * 16 + ln;

  float c0 = 0.f, c1 = 0.f;
  float mS = -3e38f, lS = 0.f, ctxA = 0.f;

  v8s xh_c, xl_c;
  ld8split(x, ((size_t)aRow * 512) * 32 + lq * 8, isbf, xh_c, xl_c);

  // t: L0 -> h0[t]; L1 -> h1[t-1]; attn+ctx consume h1[t-2]
#pragma unroll 1
  for (int t = 0; t < 514; ++t) {
    const int rB = (t + 1) & 1, wB = t & 1;
    // tagged stage: h0[t-1] (parity rB, tag t), h1[t-2] (parity wB, tag t)
    stage_enc(h0s, h1s,
              H0 + (size_t)rB * 65536 + grp * 4096,
              H1 + (size_t)wB * 65536 + grp * 4096,
              tid, (u32)(u16)t, t <= 512);
    v8s xh_n, xl_n;
    {
      int tn = (t + 1 < 512) ? t + 1 : 511;
      ld8split(x, ((size_t)aRow * 512 + tn) * 32 + lq * 8, isbf, xh_n, xl_n);
    }
    __syncthreads();   // sync1: staging complete

    v4f acc0 = {0, 0, 0, 0}, acc1 = {0, 0, 0, 0}, accA0 = {0, 0, 0, 0}, accA1 = {0, 0, 0, 0};
    acc0 = MFMA(xh_c, W0F[0], acc0);
    if (!isbf) acc0 = MFMA(xl_c, W0F[0], acc0);
#pragma unroll
    for (int kt = 0; kt < 8; ++kt) {
      const int off = ln * 264 + kt * 32 + lq * 8;
      v8s a0 = *(const v8s*)(h0s + off);
      acc0 = MFMA(a0, W0F[kt + 1], acc0);
      acc1 = MFMA(a0, W1F[kt + 8], acc1);
      v8s a1 = *(const v8s*)(h1s + off);
      acc1 = MFMA(a1, W1F[kt], acc1);
      accA0 = MFMA(a1, AWF[kt * 2], accA0);
      accA1 = MFMA(a1, AWF[kt * 2 + 1], accA1);
    }
    {
      const int bR = lq * 4;
#pragma unroll
      for (int r = 0; r < 4; ++r) {
        gb0[(bR + r) * 64 + ln * 4 + wv] = acc0[r];
        gb1[(bR + r) * 64 + ln * 4 + wv] = acc1[r];
        eP[(bR + r) * 132 + (2 * wv) * 16 + ln] = accA0[r];
        eP[(bR + r) * 132 + (2 * wv + 1) * 16 + ln] = accA1[r];
      }
    }
    float h1v = bf2f(h1s[urow * 264 + gUnit]);   // hoisted: h1s not read after sync2
    __syncthreads();   // sync2

    const u32 tagS = (u32)(u16)(t + 1) << 16;
    if (t < 512) {
      const float* g0 = gb0 + (urow * 16 + uu) * 4;
      float gi = g0[0] + bg0[0], gf = g0[1] + bg0[1], gg = g0[2] + bg0[2], go = g0[3] + bg0[3];
      c0 = sigf(gf) * c0 + sigf(gi) * tanhfast(gg);
      float h = sigf(go) * tanhfast(c0);
      astore32(H0 + (size_t)wB * 65536 + gRowU * 256 + gUnit, (u32)f2bf(h) | tagS);
    }
    if (t >= 1 && t < 513) {
      const float* g1 = gb1 + (urow * 16 + uu) * 4;
      float gi = g1[0] + bg1[0], gf = g1[1] + bg1[1], gg = g1[2] + bg1[2], go = g1[3] + bg1[3];
      c1 = sigf(gf) * c1 + sigf(gi) * tanhfast(gg);
      float h = sigf(go) * tanhfast(c1);
      astore32(H1 + (size_t)rB * 65536 + gRowU * 256 + gUnit, (u32)f2bf(h) | tagS);
    } else if (t == 0) {
      astore32(H1 + (size_t)rB * 65536 + gRowU * 256 + gUnit, tagS);  // h1[-1]=0, tag 1
    }
    if (t >= 2) {
      float e = 0.f;
#pragma unroll
      for (int j = 0; j < 8; ++j)
        e += tanhfast(eP[urow * 132 + uu + 16 * j]) * aVr[j];
      e += __shfl_xor(e, 1);
      e += __shfl_xor(e, 2);
      e += __shfl_xor(e, 4);
      e += __shfl_xor(e, 8);
      float nm = fmaxf(mS, e);
      float al = __expf(mS - nm), p = __expf(e - nm);
      lS = lS * al + p;
      ctxA = ctxA * al + p * h1v;
      mS = nm;
    }
    xh_c = xh_n; xl_c = xl_n;
  }
  ctx[(size_t)gRowU * 256 + gUnit] = ctxA / lS;
}

// ---------------- Decoder: 24 steps x 2 sub-steps + projection (hi/lo, tagged u64) -
__global__ __launch_bounds__(256, 1) void dec_kernel(
    const void* __restrict__ x,
    const void* __restrict__ dWih0, const void* __restrict__ dWhh0, const void* __restrict__ db0,
    const void* __restrict__ dWih1, const void* __restrict__ dWhh1, const void* __restrict__ db1,
    const void* __restrict__ qW, const void* __restrict__ qb,
    const float* __restrict__ ctx,
    u64* __restrict__ H0d, u64* __restrict__ H1d, u64* __restrict__ dinpG,
    void* __restrict__ out, const int* __restrict__ flagp) {
  __shared__ u16 sAhi[16 * 264], sAlo[16 * 264], sBhi[16 * 264], sBlo[16 * 264];
  __shared__ float gb[16 * 64];
  __shared__ float dinpS[16];

  const int isbf = *flagp;
  const int tid = threadIdx.x, blk = blockIdx.x;
  const int grp = blk & 15, gs = blk >> 4;
  const int lane = tid & 63, wv = tid >> 6;
  const int ln = lane & 15, lq = lane >> 4;

  v8s W0F[8], W1F[16];
  {
    const int gw = wv * 256 + gs * 16 + ln;
    const int kq = lq * 8;
#pragma unroll
    for (int kt = 0; kt < 8; ++kt) {
      W0F[kt]     = ld8hi(dWhh0, (size_t)gw * 256 + kt * 32 + kq, isbf);
      W1F[kt]     = ld8hi(dWhh1, (size_t)gw * 256 + kt * 32 + kq, isbf);
      W1F[kt + 8] = ld8hi(dWih1, (size_t)gw * 256 + kt * 32 + kq, isbf);
    }
  }
  const int urow = tid >> 4, uu = tid & 15;
  float bg0[4], bg1[4], w0v[4];
#pragma unroll
  for (int g = 0; g < 4; ++g) {
    bg0[g] = ldIn(db0, g * 256 + gs * 16 + uu, isbf);
    bg1[g] = ldIn(db1, g * 256 + gs * 16 + uu, isbf);
    w0v[g] = ldIn(dWih0, g * 256 + gs * 16 + uu, isbf);
  }
  const int gRowU = grp * 16 + urow;
  const int gUnit = gs * 16 + uu;

  float c0 = ctx[(size_t)gRowU * 256 + gUnit];
  float c1 = c0;

#pragma unroll 1
  for (int t = 0; t < 24; ++t) {
    const int pPrev = (t + 1) & 1, pCur = t & 1;
    // ---- sub-step A: layer-0 cell ----
    if (t == 0) {
      stage_f32(sAhi, sAlo, ctx + (size_t)grp * 16 * 256, tid);
      if (tid < 16)
        dinpS[tid] = ldIn(x, ((size_t)(grp * 16 + tid) * 512 + 511) * 32 + 31, isbf);
    } else {
      stage_dec(sAhi, sAlo, H0d + (size_t)pPrev * 65536 + grp * 4096, tid, (u32)(2 * t - 1));
      if (tid < 16) {
        u64 w;
        do { w = aload64(dinpG + pPrev * 256 + grp * 16 + tid); } while ((u32)(w >> 32) != (u32)(2 * t));
        dinpS[tid] = __uint_as_float((u32)w);
      }
    }
    __syncthreads();
    v4f acc = {0, 0, 0, 0};
#pragma unroll
    for (int kt = 0; kt < 8; ++kt) {
      const int off = ln * 264 + kt * 32 + lq * 8;
      acc = MFMA(*(const v8s*)(sAhi + off), W0F[kt], acc);
      acc = MFMA(*(const v8s*)(sAlo + off), W0F[kt], acc);
    }
    {
      const int bR = lq * 4;
#pragma unroll
      for (int r = 0; r < 4; ++r) gb[(bR + r) * 64 + ln * 4 + wv] = acc[r];
    }
    float di = dinpS[urow];   // hoisted: dinpS not read after sync
    __syncthreads();
    {
      const float* g0 = gb + (urow * 16 + uu) * 4;
      float gi = g0[0] + bg0[0] + di * w0v[0];
      float gf = g0[1] + bg0[1] + di * w0v[1];
      float gg = g0[2] + bg0[2] + di * w0v[2];
      float go = g0[3] + bg0[3] + di * w0v[3];
      c0 = sigf(gf) * c0 + sigf(gi) * tanhfast(gg);
      float h = sigf(go) * tanhfast(c0);
      u16 hh = f2bf(h); u16 hl = f2bf(h - bf2f(hh));
      astore64(H0d + (size_t)pCur * 65536 + gRowU * 256 + gUnit,
               (u64)hh | ((u64)hl << 16) | ((u64)(u32)(2 * t + 1) << 32));
    }
    // ---- sub-step B: layer-1 cell ----
    if (t == 0) stage_f32(sBhi, sBlo, ctx + (size_t)grp * 16 * 256, tid);
    else stage_dec(sBhi, sBlo, H1d + (size_t)pPrev * 65536 + grp * 4096, tid, (u32)(2 * t));
    stage_dec(sAhi, sAlo, H0d + (size_t)pCur * 65536 + grp * 4096, tid, (u32)(2 * t + 1));
    __syncthreads();
    v4f a1 = {0, 0, 0, 0};
#pragma unroll
    for (int kt = 0; kt < 8; ++kt) {
      const int off = ln * 264 + kt * 32 + lq * 8;
      a1 = MFMA(*(const v8s*)(sBhi + off), W1F[kt], a1);
      a1 = MFMA(*(const v8s*)(sBlo + off), W1F[kt], a1);
      a1 = MFMA(*(const v8s*)(sAhi + off), W1F[kt + 8], a1);
      a1 = MFMA(*(const v8s*)(sAlo + off), W1F[kt + 8], a1);
    }
    {
      const int bR = lq * 4;
#pragma unroll
      for (int r = 0; r < 4; ++r) gb[(bR + r) * 64 + ln * 4 + wv] = a1[r];
    }
    __syncthreads();
    {
      const float* g1 = gb + (urow * 16 + uu) * 4;
      float gi = g1[0] + bg1[0], gf = g1[1] + bg1[1], gg = g1[2] + bg1[2], go = g1[3] + bg1[3];
      c1 = sigf(gf) * c1 + sigf(gi) * tanhfast(gg);
      float h = sigf(go) * tanhfast(c1);
      u16 hh = f2bf(h); u16 hl = f2bf(h - bf2f(hh));
      astore64(H1d + (size_t)pCur * 65536 + gRowU * 256 + gUnit,
               (u64)hh | ((u64)hl << 16) | ((u64)(u32)(2 * t + 2) << 32));
      if (gUnit == 0)
        astore64(dinpG + pCur * 256 + gRowU,
                 (u64)__float_as_uint(h) | ((u64)(u32)(2 * t + 2) << 32));
    }
  }
  // projection: stage h1d[23] (parity 1, tag 48) into LDS, then compute
  stage_dec(sAhi, sAlo, H1d + (size_t)65536 + grp * 4096, tid, 48u);
  __syncthreads();
  if (gs < 12 && tid < 96) {
    int r = tid / 6, p = tid % 6;
    int qo = gs * 6 + p, row = grp * 16 + r;
    float s = ldIn(qb, qo, isbf);
    for (int h = 0; h < 256; ++h)
      s += (bf2f(sAhi[r * 264 + h]) + bf2f(sAlo[r * 264 + h])) * ldIn(qW, (size_t)qo * 256 + h, isbf);
    if (isbf) ((u16*)out)[row * 72 + qo] = f2bf(s);
    else      ((float*)out)[row * 72 + qo] = s;
  }
}

extern "C" void kernel_launch(void* const* d_in, const int* in_sizes, int n_in,
                              void* d_out, int out_size, void* d_ws, size_t ws_size,
                              hipStream_t stream) {
  const void* x     = d_in[0];
  const void* eWih0 = d_in[1];
  const void* eWhh0 = d_in[2];
  const void* eb0   = d_in[3];
  const void* eWih1 = d_in[4];
  const void* eWhh1 = d_in[5];
  const void* eb1   = d_in[6];
  const void* dWih0 = d_in[7];
  const void* dWhh0 = d_in[8];
  const void* db0   = d_in[9];
  const void* dWih1 = d_in[10];
  const void* dWhh1 = d_in[11];
  const void* db1   = d_in[12];
  const void* aW    = d_in[13];
  const void* aV    = d_in[14];
  const void* qW    = d_in[15];
  const void* qb    = d_in[16];

  char* wsb = (char*)d_ws;
  u32*   H0    = (u32*)(wsb + 0);              // [2][256][256] u32 = 524288 B
  u32*   H1    = (u32*)(wsb + 524288);         // 524288 -> 1048576
  int*   flag  = (int*)(wsb + 1048576);        // 256    -> 1048832
  float* ctx   = (float*)(wsb + 1048832);      // 262144 -> 1310976
  u64*   dinpG = (u64*)(wsb + 1310976);        // [2][256] u64 = 4096 -> 1315072
  u64*   H0d   = (u64*)(wsb + 1315072);        // [2][256][256] u64 = 1048576 -> 2363648
  u64*   H1d   = (u64*)(wsb + 2363648);        // 1048576 -> 3412224
  // total ws: 3,412,224 bytes

  // zero H0/H1 (tag 0 == expected tag at t=0); tagged buffers self-validate
  hipMemsetAsync(wsb, 0, 1048576, stream);

  sniff_kernel<<<1, 256, 0, stream>>>((const u16*)eWhh0, flag);
  enc_kernel<<<256, 256, 0, stream>>>(x, eWih0, eWhh0, eb0, eWih1, eWhh1, eb1,
                                      aW, aV, H0, H1, ctx, flag);
  dec_kernel<<<256, 256, 0, stream>>>(x, dWih0, dWhh0, db0, dWih1, dWhh1, db1,
                                      qW, qb, ctx, H0d, H1d, dinpG,
                                      d_out, flag);
}